// Round 12
// baseline (163.036 us; speedup 1.0000x reference)
//
#include <hip/hip_runtime.h>

// ---------------------------------------------------------------------------
// ConvFeatureExtractor: profile = rownorm( freq @ softmax(matches/T, axis=1)^T )
//   matches[f,i] = Thi[f, i>>6] + Tlo[f, i&63]  (separable!), F=8192, M=4096,
//   B=1024, K=6.  =>  probs[f,i] = e1[f,i>>6] * e2[f,i&63],  Z = (sum e1)(sum e2).
// R18: attack LDS read amplification + MFMA shape. R17's decisive null
//   (2x occupancy, zero change) -> limiter is per-CU, scaling with waves:
//   LDS traffic (128 b128-reads +32 GLD16-writes per CU per kt ~ 65% of the
//   2700-cyc period). Changes on the proven R10 skeleton:
//   (1) wave split 2m x 2n (wave tile 32x64): A-rows read by 2 waves not 4
//       -> per-CU ds_reads halved (64/kt).
//   (2) mfma_f32_32x32x16_bf16: 8 MFMA/wave/kt (was 16), +20% FLOP/cyc.
//       C/D: col=lane&31, row=(reg&3)+8*(reg>>2)+4*(lane>>5) [m74/m101];
//       A: row=lane&31, k=(lane>>5)*8+j -> 1 b128/K16-chunk, swz key row&7.
//   e1 fold unchanged (col per-lane -> scalar fold of f32x16 P).
//   Ledger: R7/8 ports, R14 k-rot, R16 locality, R17 occupancy = null;
//   R11 no-LDS, R12 barrier, R13 cp-norm, R15 1-wave = regress.
// ---------------------------------------------------------------------------

typedef __bf16  bf16x8 __attribute__((ext_vector_type(8)));
typedef float   f32x4  __attribute__((ext_vector_type(4)));
typedef float   f32x16 __attribute__((ext_vector_type(16)));

#define GLD16(gp, lp)                                                          \
  __builtin_amdgcn_global_load_lds(                                            \
      (const __attribute__((address_space(1))) void*)(gp),                     \
      (__attribute__((address_space(3))) void*)(lp), 16, 0, 0)

__device__ __forceinline__ short f2bf(float x) {
  unsigned u = __float_as_uint(x);
  unsigned r = (u + 0x7fffu + ((u >> 16) & 1u)) >> 16;   // RNE
  return (short)r;
}

__device__ __forceinline__ float wave_max(float v) {
  #pragma unroll
  for (int off = 32; off; off >>= 1) v = fmaxf(v, __shfl_xor(v, off, 64));
  return v;
}
__device__ __forceinline__ float wave_sum(float v) {
  #pragma unroll
  for (int off = 32; off; off >>= 1) v += __shfl_xor(v, off, 64);
  return v;
}

// ---------------- k1: prep = cast (blocks 0..4095) + tables (4096..6143) ----
__global__ __launch_bounds__(256) void prep_kernel(const float* __restrict__ freq,
                                                   short* __restrict__ freqb,
                                                   const float* __restrict__ kp,
                                                   const float* __restrict__ temp,
                                                   float* __restrict__ E1t,
                                                   float* __restrict__ E2) {
  if (blockIdx.x < 4096) {
    int idx = blockIdx.x * 256 + threadIdx.x;
    float4 v = ((const float4*)freq)[idx];
    short4 o;
    o.x = f2bf(v.x); o.y = f2bf(v.y); o.z = f2bf(v.z); o.w = f2bf(v.w);
    ((short4*)freqb)[idx] = o;
  } else {
    const int t = threadIdx.x;
    const int lane = t & 63, wave = t >> 6;
    const int f = (blockIdx.x - 4096) * 4 + wave;
    const float* P = kp + f * 24;
    const int d0 = (lane >> 4) & 3, d1 = (lane >> 2) & 3, d2 = lane & 3;
    const float thi = P[d0 * 6 + 0] + P[d1 * 6 + 1] + P[d2 * 6 + 2];
    const float tlo = P[d0 * 6 + 3] + P[d1 * 6 + 4] + P[d2 * 6 + 5];
    const float mxhi = wave_max(thi), mxlo = wave_max(tlo);
    const float invT = 1.0f / temp[0];
    const float e1 = __expf((thi - mxhi) * invT);
    const float e2 = __expf((tlo - mxlo) * invT);
    const float s1 = wave_sum(e1), s2 = wave_sum(e2);
    const float invZ = 1.0f / (s1 * s2);
    E1t[lane * 8192 + f] = e1 * invZ;
    E2[(size_t)f * 64 + lane] = e2;
  }
}

// ---------------- k2: GEMM pooled = A(1024x4096) * B^T, B[f,i]=e1[f,i>>6]e2[f,i&63]
// TM=64, TN=128, BK=64; grid 1024 blocks (4/CU), 4 waves 2Mx2N (wave 32x64).
// 32x32x16 MFMA: per wave per kt 4 a-frags (b128), 2 chains x 4 chained MFMA.
// 3-deep 8KB A buffers, 1 barrier/kt, counted vmcnt(4), XCD remap.
__global__ __launch_bounds__(256, 4) void gemm_kernel(const short* __restrict__ A,
                                                      const float* __restrict__ E1t,
                                                      const float* __restrict__ E2,
                                                      float* __restrict__ C) {
  __shared__ short As[3][64 * 64];               // 3 x 8 KiB rotating buffers

  const int t = threadIdx.x;
  const int lane = t & 63, wave = t >> 6;
  const int l31 = lane & 31, l5 = lane >> 5;     // 32x32 operand coords

  // XCD remap: d -> XCD k = d%8 owns L in [128k,128k+128) = m-strips {2k,2k+1}.
  const int d  = blockIdx.y * 64 + blockIdx.x;
  const int L  = (d & 7) * 128 + (d >> 3);
  const int m0 = (L >> 6) * 64;                  // batch tile (16 strips)
  const int n0 = (L & 63) * 128;                 // filter tile (64 strips)
  const int wm = (wave & 1) * 32;                // wave m-offset (2 waves in M)
  const int wn = (wave >> 1) * 64;               // wave n-offset (2 waves in N)

  f32x16 acc[2];
  #pragma unroll
  for (int nf = 0; nf < 2; nf++)
    #pragma unroll
    for (int x = 0; x < 16; x++) acc[nf][x] = 0.f;

  // constant bf16 e2 fragments (B operand, 32x32x16): lane holds
  // col = ncol[nf] = n0+wn+nf*32+l31, k = kc*16 + l5*8 + j (j=0..7)
  int ncol[2];
  #pragma unroll
  for (int nf = 0; nf < 2; nf++) ncol[nf] = n0 + wn + nf * 32 + l31;
  bf16x8 e2f[4][2];                              // [kc][nf]
  #pragma unroll
  for (int nf = 0; nf < 2; nf++)
    #pragma unroll
    for (int kc = 0; kc < 4; kc++) {
      const float* p = E2 + (size_t)ncol[nf] * 64 + kc * 16 + l5 * 8;
      float4 lo = *(const float4*)p, hi = *(const float4*)(p + 4);
      bf16x8 bb;
      bb[0] = (__bf16)lo.x; bb[1] = (__bf16)lo.y;
      bb[2] = (__bf16)lo.z; bb[3] = (__bf16)lo.w;
      bb[4] = (__bf16)hi.x; bb[5] = (__bf16)hi.y;
      bb[6] = (__bf16)hi.z; bb[7] = (__bf16)hi.w;
      e2f[kc][nf] = bb;
    }

  // staging (R10 pattern, unchanged): wave w stages chunks 2w, 2w+1.
  const int lane_row = lane >> 3;                      // 0..7 within 8-row chunk
  const int src_col = ((lane & 7) ^ lane_row) * 8;     // swizzled global col (shorts)
  const int swA = l31 & 7;                             // reader swizzle key (= row&7)
  const int chunk = wave * 2;
  const short* Abase = A + (size_t)(m0 + lane_row) * 4096 + src_col;

  #define STG(kt, buf) do {                                                    \
    GLD16(Abase + (size_t)((chunk + 0) * 8) * 4096 + (kt) * 64,                \
          &As[buf][(chunk + 0) * 512 + lane * 8]);                             \
    GLD16(Abase + (size_t)((chunk + 1) * 8) * 4096 + (kt) * 64,                \
          &As[buf][(chunk + 1) * 512 + lane * 8]);                             \
  } while (0)

  // prologue: S(0), e1(0), S(1)  -> 6 VMEM outstanding
  STG(0, 0);
  float e1n[2], e1c[2];
  #pragma unroll
  for (int nf = 0; nf < 2; nf++) e1n[nf] = E1t[ncol[nf]];
  STG(1, 1);

  #pragma unroll 1
  for (int kt = 0; kt < 64; ++kt) {
    const int cb = kt % 3;
    const int sb = (kt + 2) % 3;
    const int tn = (kt + 1 > 63) ? 63 : kt + 1;        // tail: dummy reload
    const int ts = (kt + 2 > 63) ? 63 : kt + 2;        // tail: dummy restage

    asm volatile("s_waitcnt vmcnt(4)" ::: "memory");   // S(kt) landed
    __builtin_amdgcn_s_barrier();                      // publish tile kt

    // A-frags: row = wm+l31, k-in-tile = kc*16 + l5*8 + j
    // logical col-block = kc*2 + l5, XOR row&7 (staged swizzle inverse)
    bf16x8 a[4];
    #pragma unroll
    for (int kc = 0; kc < 4; kc++)
      a[kc] = *(const bf16x8*)&As[cb][(wm + l31) * 64 +
                                      (((kc * 2 + l5) ^ swA) * 8)];

    #pragma unroll
    for (int nf = 0; nf < 2; nf++) e1c[nf] = e1n[nf];
    #pragma unroll
    for (int nf = 0; nf < 2; nf++) e1n[nf] = E1t[tn * 8192 + ncol[nf]]; // +2 VMEM
    STG(ts, sb);                                                        // +2 VMEM

    __builtin_amdgcn_s_setprio(1);
    #pragma unroll
    for (int nf = 0; nf < 2; nf++) {
      f32x16 P;
      #pragma unroll
      for (int x = 0; x < 16; x++) P[x] = 0.f;
      #pragma unroll
      for (int kc = 0; kc < 4; kc++)
        P = __builtin_amdgcn_mfma_f32_32x32x16_bf16(a[kc], e2f[kc][nf], P, 0, 0, 0);
      const float s = e1c[nf];
      #pragma unroll
      for (int x = 0; x < 16; x++) acc[nf][x] += s * P[x];  // f32 fold of e1
    }
    __builtin_amdgcn_s_setprio(0);
    // no bottom barrier: restage target (kt+2)%3 last read at kt-1, ordered
    // by this kt's top barrier.
  }

  asm volatile("s_waitcnt vmcnt(0)" ::: "memory");     // drain tail dummies

  // epilogue: 32x32 C/D layout col=lane&31, row=(r&3)+8*(r>>2)+4*(lane>>5)
  #pragma unroll
  for (int nf = 0; nf < 2; nf++) {
    #pragma unroll
    for (int r = 0; r < 16; r++) {
      const int brow = m0 + wm + (r & 3) + 8 * (r >> 2) + 4 * l5;
      C[(size_t)brow * 8192 + ncol[nf]] = acc[nf][r];
    }
  }
  #undef STG
}

// ---------------- k3: row-normalize d_out (1024 rows of 8192) ----------------
__global__ __launch_bounds__(256) void norm_kernel(float* __restrict__ out) {
  const int b = blockIdx.x;
  const int t = threadIdx.x;
  const int lane = t & 63, wave = t >> 6;
  __shared__ float red[4];

  float4* row = (float4*)(out + (size_t)b * 8192);   // 2048 float4
  float4 v[8];
  float s = 0.0f;
  #pragma unroll
  for (int q = 0; q < 8; q++) {
    v[q] = row[q * 256 + t];
    s += (v[q].x + v[q].y) + (v[q].z + v[q].w);
  }
  float ws = wave_sum(s);
  if (lane == 0) red[wave] = ws;
  __syncthreads();
  float tot = (red[0] + red[1]) + (red[2] + red[3]);
  float inv = 1.0f / tot;
  #pragma unroll
  for (int q = 0; q < 8; q++) {
    v[q].x *= inv; v[q].y *= inv; v[q].z *= inv; v[q].w *= inv;
    row[q * 256 + t] = v[q];
  }
}

// ---------------------------------------------------------------------------
extern "C" void kernel_launch(void* const* d_in, const int* in_sizes, int n_in,
                              void* d_out, int out_size, void* d_ws, size_t ws_size,
                              hipStream_t stream) {
  const float* freq    = (const float*)d_in[0];   // 1024*4096
  const float* kparams = (const float*)d_in[1];   // 8192*4*6
  const float* temp    = (const float*)d_in[2];   // 1
  // d_in[3] = kmer_idcs (recomputed analytically in-kernel)

  float* out = (float*)d_out;                     // 1024*8192 f32

  short* freqb = (short*)d_ws;                    // 1024*4096 bf16 = 8 MiB
  float* E1t   = (float*)(freqb + (size_t)1024 * 4096);  // 64*8192 f32 = 2 MiB
  float* E2    = E1t + (size_t)64 * 8192;                // 8192*64 f32 = 2 MiB

  prep_kernel<<<6144, 256, 0, stream>>>(freq, freqb, kparams, temp, E1t, E2);
  gemm_kernel<<<dim3(64, 16), 256, 0, stream>>>(freqb, E1t, E2, out);
  norm_kernel<<<1024, 256, 0, stream>>>(out);
}

// Round 13
// 154.669 us; speedup vs baseline: 1.0541x; 1.0541x over previous
//
#include <hip/hip_runtime.h>

// ---------------------------------------------------------------------------
// ConvFeatureExtractor: profile = rownorm( freq @ softmax(matches/T, axis=1)^T )
//   matches[f,i] = Thi[f, i>>6] + Tlo[f, i&63]  (separable!), F=8192, M=4096,
//   B=1024, K=6.  =>  probs[f,i] = e1[f,i>>6] * e2[f,i&63],  Z = (sum e1)(sum e2).
// R19: halve the sync frequency. R18 showed LDS volume isn't the limiter
//   (halved reads, same time, +conflicts -> reverted 32x32). R17 showed
//   occupancy isn't. Last untouched knob: the per-iteration convoy
//   {vmcnt drain, barrier, ds-latency ramp, fold tail} paid 64x. BK=128 ->
//   32 iterations; tile stored as TWO half-tiles each in R10's exact
//   [row][64] layout (GLD16 contiguity + proven 0-conflict swizzle kept
//   verbatim). Ping-pong 2x16KB (4 blocks/CU unchanged). Stage(it+1) issued
//   right after the barrier -> full compute phase of flight -> vmcnt(0) at
//   top is cheap. Per-element MFMA/ds/fold identical to R10.
//   Ledger: R7/8 ports, R14 k-rot, R16 locality, R17 occupancy, R18 LDS-vol
//   = null; R11/R15 no-LDS/1-wave, R12 barrier, R13 cp-norm = regress.
// ---------------------------------------------------------------------------

typedef __bf16  bf16x8 __attribute__((ext_vector_type(8)));
typedef float   f32x4  __attribute__((ext_vector_type(4)));

#define GLD16(gp, lp)                                                          \
  __builtin_amdgcn_global_load_lds(                                            \
      (const __attribute__((address_space(1))) void*)(gp),                     \
      (__attribute__((address_space(3))) void*)(lp), 16, 0, 0)

__device__ __forceinline__ short f2bf(float x) {
  unsigned u = __float_as_uint(x);
  unsigned r = (u + 0x7fffu + ((u >> 16) & 1u)) >> 16;   // RNE
  return (short)r;
}

__device__ __forceinline__ float wave_max(float v) {
  #pragma unroll
  for (int off = 32; off; off >>= 1) v = fmaxf(v, __shfl_xor(v, off, 64));
  return v;
}
__device__ __forceinline__ float wave_sum(float v) {
  #pragma unroll
  for (int off = 32; off; off >>= 1) v += __shfl_xor(v, off, 64);
  return v;
}

// ---------------- k1: prep = cast (blocks 0..4095) + tables (4096..6143) ----
__global__ __launch_bounds__(256) void prep_kernel(const float* __restrict__ freq,
                                                   short* __restrict__ freqb,
                                                   const float* __restrict__ kp,
                                                   const float* __restrict__ temp,
                                                   float* __restrict__ E1t,
                                                   float* __restrict__ E2) {
  if (blockIdx.x < 4096) {
    int idx = blockIdx.x * 256 + threadIdx.x;
    float4 v = ((const float4*)freq)[idx];
    short4 o;
    o.x = f2bf(v.x); o.y = f2bf(v.y); o.z = f2bf(v.z); o.w = f2bf(v.w);
    ((short4*)freqb)[idx] = o;
  } else {
    const int t = threadIdx.x;
    const int lane = t & 63, wave = t >> 6;
    const int f = (blockIdx.x - 4096) * 4 + wave;
    const float* P = kp + f * 24;
    const int d0 = (lane >> 4) & 3, d1 = (lane >> 2) & 3, d2 = lane & 3;
    const float thi = P[d0 * 6 + 0] + P[d1 * 6 + 1] + P[d2 * 6 + 2];
    const float tlo = P[d0 * 6 + 3] + P[d1 * 6 + 4] + P[d2 * 6 + 5];
    const float mxhi = wave_max(thi), mxlo = wave_max(tlo);
    const float invT = 1.0f / temp[0];
    const float e1 = __expf((thi - mxhi) * invT);
    const float e2 = __expf((tlo - mxlo) * invT);
    const float s1 = wave_sum(e1), s2 = wave_sum(e2);
    const float invZ = 1.0f / (s1 * s2);
    E1t[lane * 8192 + f] = e1 * invZ;
    E2[(size_t)f * 64 + lane] = e2;
  }
}

// ---------------- k2: GEMM pooled = A(1024x4096) * B^T, B[f,i]=e1[f,i>>6]e2[f,i&63]
// TM=64, TN=128, BK=128 (2 x 64-halves); 32 iterations; grid 1024 (4/CU),
// 4 waves 1Mx4N (wave 64x32). Ping-pong 2x16KB A buffers, each buffer =
// 2 half-tiles in R10's [row][64] layout. 1 vmcnt(0)+barrier per iteration.
__global__ __launch_bounds__(256, 4) void gemm_kernel(const short* __restrict__ A,
                                                      const float* __restrict__ E1t,
                                                      const float* __restrict__ E2,
                                                      float* __restrict__ C) {
  __shared__ short As[2][2][64 * 64];            // [buf][half][row*64]

  const int t = threadIdx.x;
  const int lane = t & 63, wave = t >> 6;
  const int quad = lane >> 4, l16 = lane & 15;

  // XCD remap: d -> XCD k = d%8 owns L in [128k,128k+128) = m-strips {2k,2k+1}.
  const int d  = blockIdx.y * 64 + blockIdx.x;
  const int L  = (d & 7) * 128 + (d >> 3);
  const int m0 = (L >> 6) * 64;                  // batch tile (16 strips)
  const int n0 = (L & 63) * 128;                 // filter tile (64 strips)
  const int wn = wave * 32;                      // wave's n-offset

  f32x4 acc[4][2];
  #pragma unroll
  for (int i = 0; i < 4; i++)
    #pragma unroll
    for (int j = 0; j < 2; j++) acc[i][j] = (f32x4){0.f, 0.f, 0.f, 0.f};

  // constant bf16 e2 fragments: lane (l16,quad) of frag (ks,j) covers
  // k = (ks*4+quad)*8 + 0..7 for filter row nrow[j]
  int nrow[2];
  #pragma unroll
  for (int j = 0; j < 2; j++) nrow[j] = n0 + wn + j * 16 + l16;
  bf16x8 e2f[2][2];
  #pragma unroll
  for (int j = 0; j < 2; j++)
    #pragma unroll
    for (int ks = 0; ks < 2; ks++) {
      const float* p = E2 + (size_t)nrow[j] * 64 + (ks * 4 + quad) * 8;
      float4 lo = *(const float4*)p, hi = *(const float4*)(p + 4);
      bf16x8 bb;
      bb[0] = (__bf16)lo.x; bb[1] = (__bf16)lo.y;
      bb[2] = (__bf16)lo.z; bb[3] = (__bf16)lo.w;
      bb[4] = (__bf16)hi.x; bb[5] = (__bf16)hi.y;
      bb[6] = (__bf16)hi.z; bb[7] = (__bf16)hi.w;
      e2f[ks][j] = bb;
    }

  const int lane_row = lane >> 3;                      // 0..7 within 8-row chunk
  const int src_col = ((lane & 7) ^ lane_row) * 8;     // swizzled col within half
  const int sw = l16 & 7;                              // reader swizzle key (= row&7)
  const int chunk = wave * 2;                          // wave stages chunks 2w, 2w+1
  const short* Abase = A + (size_t)(m0 + lane_row) * 4096 + src_col;

  // stage iteration it (k = it*128 .. +127) into buf: per wave 4 GLD16
  // (2 row-chunks x 2 k-halves); half h keeps R10's exact layout.
  #define STG(it, buf) do {                                                    \
    _Pragma("unroll")                                                          \
    for (int c = 0; c < 2; c++)                                                \
      _Pragma("unroll")                                                        \
      for (int h = 0; h < 2; h++)                                              \
        GLD16(Abase + (size_t)((chunk + c) * 8) * 4096 + (it) * 128 + h * 64,  \
              &As[buf][h][(chunk + c) * 512 + lane * 8]);                      \
  } while (0)

  // prologue: stage it=0, e1(it=0) for both halves
  STG(0, 0);
  float e1n[2][2], e1c[2][2];                    // [half][j]
  #pragma unroll
  for (int h = 0; h < 2; h++)
    #pragma unroll
    for (int j = 0; j < 2; j++) e1n[h][j] = E1t[h * 8192 + nrow[j]];

  const f32x4 Z4 = (f32x4){0.f, 0.f, 0.f, 0.f};

  #pragma unroll 1
  for (int it = 0; it < 32; ++it) {
    const int cb = it & 1;
    const int tn = (it + 1 > 31) ? 31 : it + 1;        // tail: dummy restage

    // S(it) + e1(it) issued a full iteration ago -> cheap full drain.
    asm volatile("s_waitcnt vmcnt(0)" ::: "memory");
    __builtin_amdgcn_s_barrier();                      // publish tile it

    STG(tn, cb ^ 1);                                   // next tile, full phase of flight
    #pragma unroll
    for (int h = 0; h < 2; h++)
      #pragma unroll
      for (int j = 0; j < 2; j++) e1c[h][j] = e1n[h][j];
    #pragma unroll
    for (int h = 0; h < 2; h++)
      #pragma unroll
      for (int j = 0; j < 2; j++) e1n[h][j] = E1t[(2 * tn + h) * 8192 + nrow[j]];

    #pragma unroll
    for (int h = 0; h < 2; h++) {                      // two 64-wide k-halves
      bf16x8 a[4][2];
      #pragma unroll
      for (int i = 0; i < 4; i++)
        #pragma unroll
        for (int ks = 0; ks < 2; ks++)
          a[i][ks] = *(const bf16x8*)&As[cb][h][(i * 16 + l16) * 64 +
                                               (((ks * 4 + quad) ^ sw) * 8)];
      __builtin_amdgcn_s_setprio(1);
      #pragma unroll
      for (int j = 0; j < 2; j++) {
        const float s = e1c[h][j];
        const f32x4 s4 = (f32x4){s, s, s, s};
        #pragma unroll
        for (int i = 0; i < 4; i++) {
          f32x4 P = __builtin_amdgcn_mfma_f32_16x16x32_bf16(a[i][0], e2f[0][j], Z4, 0, 0, 0);
          P = __builtin_amdgcn_mfma_f32_16x16x32_bf16(a[i][1], e2f[1][j], P, 0, 0, 0);
          acc[i][j] += s4 * P;                         // f32 fold of e1
        }
      }
      __builtin_amdgcn_s_setprio(0);
    }
    // no bottom barrier: restage target cb^1 was read at it-1; those reads
    // completed before this iteration's top barrier.
  }

  asm volatile("s_waitcnt vmcnt(0)" ::: "memory");     // drain tail dummies

  // epilogue: C/D layout col=lane&15, row=quad*4+reg
  #pragma unroll
  for (int i = 0; i < 4; i++) {
    #pragma unroll
    for (int r = 0; r < 4; r++) {
      const int brow = m0 + i * 16 + quad * 4 + r;
      float* crow = C + (size_t)brow * 8192 + n0 + wn + l16;
      #pragma unroll
      for (int j = 0; j < 2; j++) crow[j * 16] = acc[i][j][r];
    }
  }
  #undef STG
}

// ---------------- k3: row-normalize d_out (1024 rows of 8192) ----------------
__global__ __launch_bounds__(256) void norm_kernel(float* __restrict__ out) {
  const int b = blockIdx.x;
  const int t = threadIdx.x;
  const int lane = t & 63, wave = t >> 6;
  __shared__ float red[4];

  float4* row = (float4*)(out + (size_t)b * 8192);   // 2048 float4
  float4 v[8];
  float s = 0.0f;
  #pragma unroll
  for (int q = 0; q < 8; q++) {
    v[q] = row[q * 256 + t];
    s += (v[q].x + v[q].y) + (v[q].z + v[q].w);
  }
  float ws = wave_sum(s);
  if (lane == 0) red[wave] = ws;
  __syncthreads();
  float tot = (red[0] + red[1]) + (red[2] + red[3]);
  float inv = 1.0f / tot;
  #pragma unroll
  for (int q = 0; q < 8; q++) {
    v[q].x *= inv; v[q].y *= inv; v[q].z *= inv; v[q].w *= inv;
    row[q * 256 + t] = v[q];
  }
}

// ---------------------------------------------------------------------------
extern "C" void kernel_launch(void* const* d_in, const int* in_sizes, int n_in,
                              void* d_out, int out_size, void* d_ws, size_t ws_size,
                              hipStream_t stream) {
  const float* freq    = (const float*)d_in[0];   // 1024*4096
  const float* kparams = (const float*)d_in[1];   // 8192*4*6
  const float* temp    = (const float*)d_in[2];   // 1
  // d_in[3] = kmer_idcs (recomputed analytically in-kernel)

  float* out = (float*)d_out;                     // 1024*8192 f32

  short* freqb = (short*)d_ws;                    // 1024*4096 bf16 = 8 MiB
  float* E1t   = (float*)(freqb + (size_t)1024 * 4096);  // 64*8192 f32 = 2 MiB
  float* E2    = E1t + (size_t)64 * 8192;                // 8192*64 f32 = 2 MiB

  prep_kernel<<<6144, 256, 0, stream>>>(freq, freqb, kparams, temp, E1t, E2);
  gemm_kernel<<<dim3(64, 16), 256, 0, stream>>>(freqb, E1t, E2, out);
  norm_kernel<<<1024, 256, 0, stream>>>(out);
}

// Round 14
// 153.165 us; speedup vs baseline: 1.0645x; 1.0098x over previous
//
#include <hip/hip_runtime.h>

// ---------------------------------------------------------------------------
// ConvFeatureExtractor: profile = rownorm( freq @ softmax(matches/T, axis=1)^T )
//   matches[f,i] = Thi[f, i>>6] + Tlo[f, i&63]  (separable!), F=8192, M=4096,
//   B=1024, K=6.  =>  probs[f,i] = e1[f,i>>6] * e2[f,i&63],  Z = (sum e1)(sum e2).
// R20: LDS address strength-reduction on R19 (70us best; BK=128, 32 iters).
//   VALUBusy 35% ~ 1800 cyc/SIMD/iter >> fold cost (~300) -> dominated by
//   per-iteration recompute of 16 ds_read addresses. They are lane-constant
//   (l16*64 + ((ks*4+quad)^sw)*8) + immediate (i*1024 + h*4096) + uniform
//   toggle (cb*16384): hoist to 2 base pointers/iter + offset immediates.
//   Everything else = R19 (2x16KB ping-pong, 1 vmcnt(0)+barrier per iter,
//   stage(it+1) with full-iteration flight, XOR swizzle, e1 f32 fold,
//   XCD remap). Ledger: R7/8/14/16/17/18 null, R11/12/13/15 regress,
//   R9 (dataflow) + R19 (sync freq) wins.
// ---------------------------------------------------------------------------

typedef __bf16  bf16x8 __attribute__((ext_vector_type(8)));
typedef float   f32x4  __attribute__((ext_vector_type(4)));

#define GLD16(gp, lp)                                                          \
  __builtin_amdgcn_global_load_lds(                                            \
      (const __attribute__((address_space(1))) void*)(gp),                     \
      (__attribute__((address_space(3))) void*)(lp), 16, 0, 0)

__device__ __forceinline__ short f2bf(float x) {
  unsigned u = __float_as_uint(x);
  unsigned r = (u + 0x7fffu + ((u >> 16) & 1u)) >> 16;   // RNE
  return (short)r;
}

__device__ __forceinline__ float wave_max(float v) {
  #pragma unroll
  for (int off = 32; off; off >>= 1) v = fmaxf(v, __shfl_xor(v, off, 64));
  return v;
}
__device__ __forceinline__ float wave_sum(float v) {
  #pragma unroll
  for (int off = 32; off; off >>= 1) v += __shfl_xor(v, off, 64);
  return v;
}

// ---------------- k1: prep = cast (blocks 0..4095) + tables (4096..6143) ----
__global__ __launch_bounds__(256) void prep_kernel(const float* __restrict__ freq,
                                                   short* __restrict__ freqb,
                                                   const float* __restrict__ kp,
                                                   const float* __restrict__ temp,
                                                   float* __restrict__ E1t,
                                                   float* __restrict__ E2) {
  if (blockIdx.x < 4096) {
    int idx = blockIdx.x * 256 + threadIdx.x;
    float4 v = ((const float4*)freq)[idx];
    short4 o;
    o.x = f2bf(v.x); o.y = f2bf(v.y); o.z = f2bf(v.z); o.w = f2bf(v.w);
    ((short4*)freqb)[idx] = o;
  } else {
    const int t = threadIdx.x;
    const int lane = t & 63, wave = t >> 6;
    const int f = (blockIdx.x - 4096) * 4 + wave;
    const float* P = kp + f * 24;
    const int d0 = (lane >> 4) & 3, d1 = (lane >> 2) & 3, d2 = lane & 3;
    const float thi = P[d0 * 6 + 0] + P[d1 * 6 + 1] + P[d2 * 6 + 2];
    const float tlo = P[d0 * 6 + 3] + P[d1 * 6 + 4] + P[d2 * 6 + 5];
    const float mxhi = wave_max(thi), mxlo = wave_max(tlo);
    const float invT = 1.0f / temp[0];
    const float e1 = __expf((thi - mxhi) * invT);
    const float e2 = __expf((tlo - mxlo) * invT);
    const float s1 = wave_sum(e1), s2 = wave_sum(e2);
    const float invZ = 1.0f / (s1 * s2);
    E1t[lane * 8192 + f] = e1 * invZ;
    E2[(size_t)f * 64 + lane] = e2;
  }
}

// ---------------- k2: GEMM pooled = A(1024x4096) * B^T, B[f,i]=e1[f,i>>6]e2[f,i&63]
// TM=64, TN=128, BK=128 (2 x 64-halves); 32 iterations; grid 1024 (4/CU),
// 4 waves 1Mx4N (wave 64x32). Ping-pong 2x16KB A buffers. 1 vmcnt(0)+barrier
// per iteration. LDS reads: 2 hoisted base ptrs + offset immediates.
__global__ __launch_bounds__(256, 4) void gemm_kernel(const short* __restrict__ A,
                                                      const float* __restrict__ E1t,
                                                      const float* __restrict__ E2,
                                                      float* __restrict__ C) {
  __shared__ short As[2][2][64 * 64];            // [buf][half][row*64]

  const int t = threadIdx.x;
  const int lane = t & 63, wave = t >> 6;
  const int quad = lane >> 4, l16 = lane & 15;

  // XCD remap: d -> XCD k = d%8 owns L in [128k,128k+128) = m-strips {2k,2k+1}.
  const int d  = blockIdx.y * 64 + blockIdx.x;
  const int L  = (d & 7) * 128 + (d >> 3);
  const int m0 = (L >> 6) * 64;                  // batch tile (16 strips)
  const int n0 = (L & 63) * 128;                 // filter tile (64 strips)
  const int wn = wave * 32;                      // wave's n-offset

  f32x4 acc[4][2];
  #pragma unroll
  for (int i = 0; i < 4; i++)
    #pragma unroll
    for (int j = 0; j < 2; j++) acc[i][j] = (f32x4){0.f, 0.f, 0.f, 0.f};

  // constant bf16 e2 fragments: lane (l16,quad) of frag (ks,j) covers
  // k = (ks*4+quad)*8 + 0..7 for filter row nrow[j]
  int nrow[2];
  #pragma unroll
  for (int j = 0; j < 2; j++) nrow[j] = n0 + wn + j * 16 + l16;
  bf16x8 e2f[2][2];
  #pragma unroll
  for (int j = 0; j < 2; j++)
    #pragma unroll
    for (int ks = 0; ks < 2; ks++) {
      const float* p = E2 + (size_t)nrow[j] * 64 + (ks * 4 + quad) * 8;
      float4 lo = *(const float4*)p, hi = *(const float4*)(p + 4);
      bf16x8 bb;
      bb[0] = (__bf16)lo.x; bb[1] = (__bf16)lo.y;
      bb[2] = (__bf16)lo.z; bb[3] = (__bf16)lo.w;
      bb[4] = (__bf16)hi.x; bb[5] = (__bf16)hi.y;
      bb[6] = (__bf16)hi.z; bb[7] = (__bf16)hi.w;
      e2f[ks][j] = bb;
    }

  const int lane_row = lane >> 3;                      // 0..7 within 8-row chunk
  const int src_col = ((lane & 7) ^ lane_row) * 8;     // swizzled col within half
  const int sw = l16 & 7;                              // reader swizzle key (= row&7)
  const int chunk = wave * 2;                          // wave stages chunks 2w, 2w+1
  const short* Abase = A + (size_t)(m0 + lane_row) * 4096 + src_col;

  // hoisted lane-constant LDS read offsets (shorts): base row + swizzled col
  const int rc0 = l16 * 64 + ((quad ^ sw) * 8);        // ks=0
  const int rc1 = l16 * 64 + (((quad + 4) ^ sw) * 8);  // ks=1

  // stage iteration it (k = it*128 .. +127) into buf: per wave 4 GLD16
  #define STG(it, buf) do {                                                    \
    _Pragma("unroll")                                                          \
    for (int c = 0; c < 2; c++)                                                \
      _Pragma("unroll")                                                        \
      for (int h = 0; h < 2; h++)                                              \
        GLD16(Abase + (size_t)((chunk + c) * 8) * 4096 + (it) * 128 + h * 64,  \
              &As[buf][h][(chunk + c) * 512 + lane * 8]);                      \
  } while (0)

  // prologue: stage it=0, e1(it=0) for both halves
  STG(0, 0);
  float e1n[2][2], e1c[2][2];                    // [half][j]
  #pragma unroll
  for (int h = 0; h < 2; h++)
    #pragma unroll
    for (int j = 0; j < 2; j++) e1n[h][j] = E1t[h * 8192 + nrow[j]];

  const f32x4 Z4 = (f32x4){0.f, 0.f, 0.f, 0.f};

  #pragma unroll 1
  for (int it = 0; it < 32; ++it) {
    const int cb = it & 1;
    const int tn = (it + 1 > 31) ? 31 : it + 1;        // tail: dummy restage

    // S(it) + e1(it) issued a full iteration ago -> cheap full drain.
    asm volatile("s_waitcnt vmcnt(0)" ::: "memory");
    __builtin_amdgcn_s_barrier();                      // publish tile it

    STG(tn, cb ^ 1);                                   // next tile, full phase of flight
    #pragma unroll
    for (int h = 0; h < 2; h++)
      #pragma unroll
      for (int j = 0; j < 2; j++) e1c[h][j] = e1n[h][j];
    #pragma unroll
    for (int h = 0; h < 2; h++)
      #pragma unroll
      for (int j = 0; j < 2; j++) e1n[h][j] = E1t[(2 * tn + h) * 8192 + nrow[j]];

    // two base pointers for the iteration; all 16 reads use constant offsets
    // (h*4096 + i*1024 shorts = 8192/2048 B immediates on ds_read_b128)
    const short* b0 = &As[cb][0][rc0];
    const short* b1 = &As[cb][0][rc1];

    #pragma unroll
    for (int h = 0; h < 2; h++) {                      // two 64-wide k-halves
      bf16x8 a[4][2];
      #pragma unroll
      for (int i = 0; i < 4; i++) {
        a[i][0] = *(const bf16x8*)(b0 + h * 4096 + i * 1024);
        a[i][1] = *(const bf16x8*)(b1 + h * 4096 + i * 1024);
      }
      __builtin_amdgcn_s_setprio(1);
      #pragma unroll
      for (int j = 0; j < 2; j++) {
        const float s = e1c[h][j];
        const f32x4 s4 = (f32x4){s, s, s, s};
        #pragma unroll
        for (int i = 0; i < 4; i++) {
          f32x4 P = __builtin_amdgcn_mfma_f32_16x16x32_bf16(a[i][0], e2f[0][j], Z4, 0, 0, 0);
          P = __builtin_amdgcn_mfma_f32_16x16x32_bf16(a[i][1], e2f[1][j], P, 0, 0, 0);
          acc[i][j] += s4 * P;                         // f32 fold of e1
        }
      }
      __builtin_amdgcn_s_setprio(0);
    }
    // no bottom barrier: restage target cb^1 was read at it-1; those reads
    // completed before this iteration's top barrier.
  }

  asm volatile("s_waitcnt vmcnt(0)" ::: "memory");     // drain tail dummies

  // epilogue: C/D layout col=lane&15, row=quad*4+reg
  #pragma unroll
  for (int i = 0; i < 4; i++) {
    #pragma unroll
    for (int r = 0; r < 4; r++) {
      const int brow = m0 + i * 16 + quad * 4 + r;
      float* crow = C + (size_t)brow * 8192 + n0 + wn + l16;
      #pragma unroll
      for (int j = 0; j < 2; j++) crow[j * 16] = acc[i][j][r];
    }
  }
  #undef STG
}

// ---------------- k3: row-normalize d_out (1024 rows of 8192) ----------------
__global__ __launch_bounds__(256) void norm_kernel(float* __restrict__ out) {
  const int b = blockIdx.x;
  const int t = threadIdx.x;
  const int lane = t & 63, wave = t >> 6;
  __shared__ float red[4];

  float4* row = (float4*)(out + (size_t)b * 8192);   // 2048 float4
  float4 v[8];
  float s = 0.0f;
  #pragma unroll
  for (int q = 0; q < 8; q++) {
    v[q] = row[q * 256 + t];
    s += (v[q].x + v[q].y) + (v[q].z + v[q].w);
  }
  float ws = wave_sum(s);
  if (lane == 0) red[wave] = ws;
  __syncthreads();
  float tot = (red[0] + red[1]) + (red[2] + red[3]);
  float inv = 1.0f / tot;
  #pragma unroll
  for (int q = 0; q < 8; q++) {
    v[q].x *= inv; v[q].y *= inv; v[q].z *= inv; v[q].w *= inv;
    row[q * 256 + t] = v[q];
  }
}

// ---------------------------------------------------------------------------
extern "C" void kernel_launch(void* const* d_in, const int* in_sizes, int n_in,
                              void* d_out, int out_size, void* d_ws, size_t ws_size,
                              hipStream_t stream) {
  const float* freq    = (const float*)d_in[0];   // 1024*4096
  const float* kparams = (const float*)d_in[1];   // 8192*4*6
  const float* temp    = (const float*)d_in[2];   // 1
  // d_in[3] = kmer_idcs (recomputed analytically in-kernel)

  float* out = (float*)d_out;                     // 1024*8192 f32

  short* freqb = (short*)d_ws;                    // 1024*4096 bf16 = 8 MiB
  float* E1t   = (float*)(freqb + (size_t)1024 * 4096);  // 64*8192 f32 = 2 MiB
  float* E2    = E1t + (size_t)64 * 8192;                // 8192*64 f32 = 2 MiB

  prep_kernel<<<6144, 256, 0, stream>>>(freq, freqb, kparams, temp, E1t, E2);
  gemm_kernel<<<dim3(64, 16), 256, 0, stream>>>(freqb, E1t, E2, out);
  norm_kernel<<<1024, 256, 0, stream>>>(out);
}